// Round 1
// baseline (232.391 us; speedup 1.0000x reference)
//
#include <hip/hip_runtime.h>
#include <hip/hip_bf16.h>
#include <cstdint>
#include <cstddef>

// ---------------------------------------------------------------------------
// GateLoop fused pipeline, bf16 MFMA GEMMs + chunked parallel scan.
// B=2, S=4096, D=1024 hard-coded.
// ---------------------------------------------------------------------------

typedef __bf16 bf16x8 __attribute__((ext_vector_type(8)));
typedef float f32x4 __attribute__((ext_vector_type(4)));

__device__ __forceinline__ void gload_lds16(const void* g, void* l) {
  __builtin_amdgcn_global_load_lds(
      (const __attribute__((address_space(1))) void*)g,
      (__attribute__((address_space(3))) void*)l,
      16, 0, 0);
}

// ---------------------------------------------------------------------------
// Weight convert + transpose: dst[n][k] = (bf16) src[k][n]
// blockIdx.z selects weight; 32x32 tiles via LDS.
// ---------------------------------------------------------------------------
__global__ __launch_bounds__(256) void wconv_k(
    const float* __restrict__ wq, const float* __restrict__ wk,
    const float* __restrict__ wv, const float* __restrict__ wa,
    const float* __restrict__ wg, const float* __restrict__ wo,
    __hip_bfloat16* __restrict__ wcatT, __hip_bfloat16* __restrict__ woT) {
  __shared__ float t[32][33];
  const float* src;
  __hip_bfloat16* dst;
  switch (blockIdx.z) {
    case 0: src = wq; dst = wcatT; break;                          // rows 0..1023   (q)
    case 1: src = wk; dst = wcatT + (size_t)1024 * 1024; break;    // rows 1024..    (k)
    case 2: src = wv; dst = wcatT + (size_t)2048 * 1024; break;    // rows 2048..    (v)
    case 3: src = wg; dst = wcatT + (size_t)3072 * 1024; break;    // rows 3072..    (g)
    case 4: src = wa; dst = wcatT + (size_t)4096 * 1024; break;    // rows 4096..    (a)
    default: src = wo; dst = woT; break;
  }
  const int n0 = blockIdx.x * 32;
  const int k0 = blockIdx.y * 32;
  const int tx = threadIdx.x, ty = threadIdx.y;  // (32, 8)
#pragma unroll
  for (int i = 0; i < 32; i += 8)
    t[ty + i][tx] = src[(size_t)(k0 + ty + i) * 1024 + n0 + tx];
  __syncthreads();
#pragma unroll
  for (int i = 0; i < 32; i += 8)
    dst[(size_t)(n0 + ty + i) * 1024 + k0 + tx] = __float2bfloat16(t[tx][ty + i]);
}

// ---------------------------------------------------------------------------
// RMSNorm (sum-of-squares variant): xn = x * gamma * sqrt(D) * rsqrt(ss+eps)
// One block per row, 256 threads x float4.
// ---------------------------------------------------------------------------
__global__ __launch_bounds__(256) void rmsnorm_k(
    const float* __restrict__ x, const float* __restrict__ gamma,
    __hip_bfloat16* __restrict__ xn) {
  const int row = blockIdx.x;
  const int tid = threadIdx.x;
  const float4 xv = ((const float4*)(x + (size_t)row * 1024))[tid];
  float ss = xv.x * xv.x + xv.y * xv.y + xv.z * xv.z + xv.w * xv.w;
#pragma unroll
  for (int off = 32; off >= 1; off >>= 1) ss += __shfl_xor(ss, off, 64);
  __shared__ float wss[4];
  if ((tid & 63) == 0) wss[tid >> 6] = ss;
  __syncthreads();
  const float total = wss[0] + wss[1] + wss[2] + wss[3];
  const float scale = rsqrtf(total + 1e-5f) * 32.0f;  // sqrt(1024) = 32
  const float4 gv = ((const float4*)gamma)[tid];
  union { __hip_bfloat16 h[4]; ushort4 u; } ob;
  ob.h[0] = __float2bfloat16(xv.x * gv.x * scale);
  ob.h[1] = __float2bfloat16(xv.y * gv.y * scale);
  ob.h[2] = __float2bfloat16(xv.z * gv.z * scale);
  ob.h[3] = __float2bfloat16(xv.w * gv.w * scale);
  ((ushort4*)(xn + (size_t)row * 1024))[tid] = ob.u;
}

// ---------------------------------------------------------------------------
// bf16 GEMM: C[m][n] = sum_k A[m][k] * Bt[n][k]
// 128x128 tile, BK=32, 4 waves (2x2), 16x16x32 MFMA, global_load_lds width 16.
// Output: n < nbcols -> bf16 to outb (ld ldb); else fp32 to outf at col n-nbcols.
// ---------------------------------------------------------------------------
__global__ __launch_bounds__(256) void gemm_bf16(
    const __hip_bfloat16* __restrict__ A, const __hip_bfloat16* __restrict__ Bt,
    int M, int N, int K,
    __hip_bfloat16* __restrict__ outb, int ldb, int nbcols,
    float* __restrict__ outf, int ldf) {
  __shared__ __align__(16) unsigned short As[128 * 32];
  __shared__ __align__(16) unsigned short Bs[128 * 32];
  const int tid = threadIdx.x;
  const int brow = blockIdx.y * 128;
  const int bcol = blockIdx.x * 128;
  const int lane = tid & 63;
  const int w = tid >> 6;
  const int wm = (w >> 1) * 64;
  const int wn = (w & 1) * 64;
  const int l16 = lane & 15;
  const int k8 = lane >> 4;

  const unsigned short* Ag = (const unsigned short*)A;
  const unsigned short* Bg = (const unsigned short*)Bt;

  const int r0 = tid >> 2;        // staging row 0..63
  const int ch = (tid & 3) * 8;   // staging k-chunk (elements)

  f32x4 acc[4][4];
#pragma unroll
  for (int i = 0; i < 4; ++i)
#pragma unroll
    for (int j = 0; j < 4; ++j) acc[i][j] = (f32x4){0.f, 0.f, 0.f, 0.f};

  for (int k0 = 0; k0 < K; k0 += 32) {
    __syncthreads();  // previous iteration's ds_reads done before overwrite
    // stage A tile (128x32) and B tile (128x32), 16B per lane per issue
    gload_lds16(Ag + (size_t)(brow + r0) * K + k0 + ch, &As[r0 * 32 + ch]);
    gload_lds16(Ag + (size_t)(brow + r0 + 64) * K + k0 + ch, &As[(r0 + 64) * 32 + ch]);
    gload_lds16(Bg + (size_t)(bcol + r0) * K + k0 + ch, &Bs[r0 * 32 + ch]);
    gload_lds16(Bg + (size_t)(bcol + r0 + 64) * K + k0 + ch, &Bs[(r0 + 64) * 32 + ch]);
    __syncthreads();  // vmcnt(0) drained by compiler before barrier

    bf16x8 af[4], bfr[4];
#pragma unroll
    for (int i = 0; i < 4; ++i)
      af[i] = *(const bf16x8*)&As[(wm + i * 16 + l16) * 32 + k8 * 8];
#pragma unroll
    for (int j = 0; j < 4; ++j)
      bfr[j] = *(const bf16x8*)&Bs[(wn + j * 16 + l16) * 32 + k8 * 8];
#pragma unroll
    for (int i = 0; i < 4; ++i)
#pragma unroll
      for (int j = 0; j < 4; ++j)
        acc[i][j] = __builtin_amdgcn_mfma_f32_16x16x32_bf16(af[i], bfr[j], acc[i][j], 0, 0, 0);
  }

  // C/D layout (m89-verified): col = lane&15, row = (lane>>4)*4 + reg
  const int mbase = brow + wm + k8 * 4;
  const int nbase = bcol + wn + l16;
#pragma unroll
  for (int i = 0; i < 4; ++i) {
#pragma unroll
    for (int j = 0; j < 4; ++j) {
      const int n = nbase + j * 16;
#pragma unroll
      for (int r = 0; r < 4; ++r) {
        const int m = mbase + i * 16 + r;
        const float v = acc[i][j][r];
        if (n < nbcols) {
          outb[(size_t)m * ldb + n] = __float2bfloat16(v);
        } else {
          outf[(size_t)m * ldf + (n - nbcols)] = v;
        }
      }
    }
  }
}

// ---------------------------------------------------------------------------
// Gated scan, chunked: S=4096 split into 32 chunks of L=128 per sequence.
// qkvg layout: [8192 tokens][4096] bf16, cols [q|k|v|g]; apre fp32 [8192][1024].
// ---------------------------------------------------------------------------
__global__ __launch_bounds__(256) void scan_pass1(
    const __hip_bfloat16* __restrict__ qkvg, const float* __restrict__ apre,
    float* __restrict__ Asum, float* __restrict__ Ysum) {
  const int bc = blockIdx.x;           // b*32 + chunk
  const int d = blockIdx.y * 256 + threadIdx.x;
  const size_t rowbase = (size_t)(bc >> 5) * 4096 + (size_t)(bc & 31) * 128;
  float y = 0.f, Ap = 1.f;
  for (int s = 0; s < 128; ++s) {
    const size_t r = rowbase + s;
    const float kk = __bfloat162float(qkvg[r * 4096 + 1024 + d]);
    const float vv = __bfloat162float(qkvg[r * 4096 + 2048 + d]);
    const float ap = apre[r * 1024 + d];
    const float a = 1.f / (1.f + __expf(-ap));
    y = fmaf(a, y, kk * vv);
    Ap *= a;
  }
  Asum[(size_t)bc * 1024 + d] = Ap;
  Ysum[(size_t)bc * 1024 + d] = y;
}

__global__ __launch_bounds__(256) void scan_pass2(
    const float* __restrict__ Asum, const float* __restrict__ Ysum,
    float* __restrict__ carry) {
  const int idx = blockIdx.x * 256 + threadIdx.x;  // 0..2047
  const int b = idx >> 10, d = idx & 1023;
  float y = 0.f;
  for (int c = 0; c < 32; ++c) {
    const size_t o = (size_t)(b * 32 + c) * 1024 + d;
    carry[o] = y;
    y = fmaf(Asum[o], y, Ysum[o]);
  }
}

__global__ __launch_bounds__(256) void scan_pass3(
    const __hip_bfloat16* __restrict__ qkvg, const float* __restrict__ apre,
    const float* __restrict__ carry, __hip_bfloat16* __restrict__ yact) {
  const int bc = blockIdx.x;
  const int d = blockIdx.y * 256 + threadIdx.x;
  const size_t rowbase = (size_t)(bc >> 5) * 4096 + (size_t)(bc & 31) * 128;
  float y = carry[(size_t)bc * 1024 + d];
  for (int s = 0; s < 128; ++s) {
    const size_t r = rowbase + s;
    const float qq = __bfloat162float(qkvg[r * 4096 + d]);
    const float kk = __bfloat162float(qkvg[r * 4096 + 1024 + d]);
    const float vv = __bfloat162float(qkvg[r * 4096 + 2048 + d]);
    const float gg = __bfloat162float(qkvg[r * 4096 + 3072 + d]);
    const float ap = apre[r * 1024 + d];
    const float a = 1.f / (1.f + __expf(-ap));
    y = fmaf(a, y, kk * vv);
    const float sg = 1.f / (1.f + __expf(-gg));
    yact[r * 1024 + d] = __float2bfloat16(qq * y * gg * sg);
  }
}

// ---------------------------------------------------------------------------
// launch
// ---------------------------------------------------------------------------
extern "C" void kernel_launch(void* const* d_in, const int* in_sizes, int n_in,
                              void* d_out, int out_size, void* d_ws, size_t ws_size,
                              hipStream_t stream) {
  const float* x     = (const float*)d_in[0];
  const float* gamma = (const float*)d_in[1];
  const float* wq    = (const float*)d_in[2];
  const float* wk    = (const float*)d_in[3];
  const float* wv    = (const float*)d_in[4];
  const float* wa    = (const float*)d_in[5];
  const float* wg    = (const float*)d_in[6];
  const float* wo    = (const float*)d_in[7];
  float* out = (float*)d_out;

  char* ws = (char*)d_ws;
  __hip_bfloat16* wcatT = (__hip_bfloat16*)(ws);              // 5120x1024 bf16 = 10,485,760
  __hip_bfloat16* woT   = (__hip_bfloat16*)(ws + 10485760);   // 1024x1024 bf16 =  2,097,152
  __hip_bfloat16* xn    = (__hip_bfloat16*)(ws + 12582912);   // 8192x1024 bf16 = 16,777,216
  __hip_bfloat16* qkvg  = (__hip_bfloat16*)(ws + 29360128);   // 8192x4096 bf16 = 67,108,864
  float*          apre  = (float*)(ws + 96468992);            // 8192x1024 f32  = 33,554,432
  __hip_bfloat16* yact  = (__hip_bfloat16*)(ws + 130023424);  // 8192x1024 bf16 = 16,777,216
  float*          Asum  = (float*)(ws + 146800640);           // 64x1024 f32
  float*          Ysum  = (float*)(ws + 147062784);
  float*          carry = (float*)(ws + 147324928);           // end ~147.6 MB

  wconv_k<<<dim3(32, 32, 6), dim3(32, 8, 1), 0, stream>>>(wq, wk, wv, wa, wg, wo, wcatT, woT);
  rmsnorm_k<<<dim3(8192), dim3(256), 0, stream>>>(x, gamma, xn);
  gemm_bf16<<<dim3(40, 64), dim3(256), 0, stream>>>(
      xn, wcatT, 8192, 5120, 1024, qkvg, 4096, 4096, apre, 1024);
  scan_pass1<<<dim3(64, 4), dim3(256), 0, stream>>>(qkvg, apre, Asum, Ysum);
  scan_pass2<<<dim3(8), dim3(256), 0, stream>>>(Asum, Ysum, carry);
  scan_pass3<<<dim3(64, 4), dim3(256), 0, stream>>>(qkvg, apre, carry, yact);
  gemm_bf16<<<dim3(8, 64), dim3(256), 0, stream>>>(
      yact, woT, 8192, 1024, 1024, (__hip_bfloat16*)nullptr, 0, 0, out, 1024);
}

// Round 2
// 220.573 us; speedup vs baseline: 1.0536x; 1.0536x over previous
//
#include <hip/hip_runtime.h>
#include <hip/hip_bf16.h>
#include <cstdint>
#include <cstddef>

// ---------------------------------------------------------------------------
// GateLoop fused pipeline. bf16 MFMA GEMMs (256x256 slice-pipelined) +
// chunked parallel scan. B=2, S=4096, D=1024 hard-coded.
// ---------------------------------------------------------------------------

typedef __bf16 bf16x8 __attribute__((ext_vector_type(8)));
typedef float f32x4 __attribute__((ext_vector_type(4)));

__device__ __forceinline__ void gload_lds16(const void* g, void* l) {
  __builtin_amdgcn_global_load_lds(
      (const __attribute__((address_space(1))) void*)g,
      (__attribute__((address_space(3))) void*)l,
      16, 0, 0);
}

// ---------------------------------------------------------------------------
// Weight convert + transpose: dst[n][k] = (bf16) src[k][n]
// ---------------------------------------------------------------------------
__global__ __launch_bounds__(256) void wconv_k(
    const float* __restrict__ wq, const float* __restrict__ wk,
    const float* __restrict__ wv, const float* __restrict__ wa,
    const float* __restrict__ wg, const float* __restrict__ wo,
    __hip_bfloat16* __restrict__ wcatT, __hip_bfloat16* __restrict__ woT) {
  __shared__ float t[32][33];
  const float* src;
  __hip_bfloat16* dst;
  switch (blockIdx.z) {
    case 0: src = wq; dst = wcatT; break;
    case 1: src = wk; dst = wcatT + (size_t)1024 * 1024; break;
    case 2: src = wv; dst = wcatT + (size_t)2048 * 1024; break;
    case 3: src = wg; dst = wcatT + (size_t)3072 * 1024; break;
    case 4: src = wa; dst = wcatT + (size_t)4096 * 1024; break;
    default: src = wo; dst = woT; break;
  }
  const int n0 = blockIdx.x * 32;
  const int k0 = blockIdx.y * 32;
  const int tx = threadIdx.x, ty = threadIdx.y;  // (32, 8)
#pragma unroll
  for (int i = 0; i < 32; i += 8)
    t[ty + i][tx] = src[(size_t)(k0 + ty + i) * 1024 + n0 + tx];
  __syncthreads();
#pragma unroll
  for (int i = 0; i < 32; i += 8)
    dst[(size_t)(n0 + ty + i) * 1024 + k0 + tx] = __float2bfloat16(t[tx][ty + i]);
}

// ---------------------------------------------------------------------------
// RMSNorm (sum-of-squares variant): xn = x * gamma * sqrt(D) * rsqrt(ss+eps)
// ---------------------------------------------------------------------------
__global__ __launch_bounds__(256) void rmsnorm_k(
    const float* __restrict__ x, const float* __restrict__ gamma,
    __hip_bfloat16* __restrict__ xn) {
  const int row = blockIdx.x;
  const int tid = threadIdx.x;
  const float4 xv = ((const float4*)(x + (size_t)row * 1024))[tid];
  float ss = xv.x * xv.x + xv.y * xv.y + xv.z * xv.z + xv.w * xv.w;
#pragma unroll
  for (int off = 32; off >= 1; off >>= 1) ss += __shfl_xor(ss, off, 64);
  __shared__ float wss[4];
  if ((tid & 63) == 0) wss[tid >> 6] = ss;
  __syncthreads();
  const float total = wss[0] + wss[1] + wss[2] + wss[3];
  const float scale = rsqrtf(total + 1e-5f) * 32.0f;  // sqrt(1024) = 32
  const float4 gv = ((const float4*)gamma)[tid];
  union { __hip_bfloat16 h[4]; ushort4 u; } ob;
  ob.h[0] = __float2bfloat16(xv.x * gv.x * scale);
  ob.h[1] = __float2bfloat16(xv.y * gv.y * scale);
  ob.h[2] = __float2bfloat16(xv.z * gv.z * scale);
  ob.h[3] = __float2bfloat16(xv.w * gv.w * scale);
  ((ushort4*)(xn + (size_t)row * 1024))[tid] = ob.u;
}

// ---------------------------------------------------------------------------
// gemm256: C[m][n] = sum_k A[m][k] * Bt[n][k]
// 256x256 tile, 8 waves (2Mx4N), K-slice ring pipeline (SK=32, 4 LDS slots),
// counted vmcnt(8), setprio around MFMA, XOR-swizzled LDS (both sides),
// XCD-bijective block swizzle. Requires M%256==0, N%256==0, K%32==0,
// grid.x*grid.y % 8 == 0.
// Output: n < nbcols -> bf16 outb (ld ldb); else fp32 outf at col n-nbcols.
// ---------------------------------------------------------------------------
__global__ __launch_bounds__(512, 2) void gemm256(
    const __hip_bfloat16* __restrict__ A, const __hip_bfloat16* __restrict__ Bt,
    int M, int N, int K,
    __hip_bfloat16* __restrict__ outb, int ldb, int nbcols,
    float* __restrict__ outf, int ldf) {
  __shared__ __align__(16) unsigned short As[4 * 8192];  // 4 slots x 256x32
  __shared__ __align__(16) unsigned short Bs[4 * 8192];

  const int tid = threadIdx.x;
  // XCD-aware bijective swizzle (nwg % 8 == 0 guaranteed by launcher)
  const int nwg = gridDim.x * gridDim.y;
  const int bid = blockIdx.y * gridDim.x + blockIdx.x;
  const int swz = (bid & 7) * (nwg >> 3) + (bid >> 3);
  const int brow = (swz / gridDim.x) * 256;
  const int bcol = (swz % gridDim.x) * 256;

  const unsigned short* Ag = (const unsigned short*)A + (size_t)brow * K;
  const unsigned short* Bg = (const unsigned short*)Bt + (size_t)bcol * K;

  // staging geometry: 512 threads x 16B; one issue covers 128 rows x 32k.
  const int srow = tid >> 2;                          // 0..127
  const int sch8 = (((tid & 3) ^ ((srow >> 1) & 3)) << 3);  // swizzled k-chunk (elems)

  auto stageA = [&](int sl) {
    unsigned short* dst = As + ((sl & 3) << 13);
    const int k0 = sl << 5;
    gload_lds16(Ag + (size_t)srow * K + k0 + sch8, dst + tid * 8);
    gload_lds16(Ag + (size_t)(srow + 128) * K + k0 + sch8, dst + 4096 + tid * 8);
  };
  auto stageB = [&](int sl) {
    unsigned short* dst = Bs + ((sl & 3) << 13);
    const int k0 = sl << 5;
    gload_lds16(Bg + (size_t)srow * K + k0 + sch8, dst + tid * 8);
    gload_lds16(Bg + (size_t)(srow + 128) * K + k0 + sch8, dst + 4096 + tid * 8);
  };

  // wave/fragment geometry
  const int lane = tid & 63;
  const int wid = tid >> 6;
  const int wr = wid >> 2;   // 0..1 : row half
  const int wc = wid & 3;    // 0..3 : col quarter
  const int l16 = lane & 15;
  const int k8 = lane >> 4;

  int aoff[8], boff[4];
#pragma unroll
  for (int m = 0; m < 8; ++m) {
    const int r = wr * 128 + m * 16 + l16;
    aoff[m] = r * 32 + ((k8 ^ ((r >> 1) & 3)) << 3);
  }
#pragma unroll
  for (int n = 0; n < 4; ++n) {
    const int r = wc * 64 + n * 16 + l16;
    boff[n] = r * 32 + ((k8 ^ ((r >> 1) & 3)) << 3);
  }

  f32x4 acc[8][4];
#pragma unroll
  for (int m = 0; m < 8; ++m)
#pragma unroll
    for (int n = 0; n < 4; ++n) acc[m][n] = (f32x4){0.f, 0.f, 0.f, 0.f};

  const int NS = K >> 5;
  // prologue: 3 slices in flight
  stageA(0); stageB(0);
  stageA(1); stageB(1);
  stageA(2); stageB(2);
  asm volatile("s_waitcnt vmcnt(8)" ::: "memory");  // slice 0 landed
  __builtin_amdgcn_s_barrier();

  for (int s = 0; s < NS; ++s) {
    const unsigned short* As_s = As + ((s & 3) << 13);
    const unsigned short* Bs_s = Bs + ((s & 3) << 13);
    bf16x8 af[8], bfr[4];
    // ---- phase 0: read A frags + B n0/n1, stage A(s+3), MFMA n0/n1 ----
#pragma unroll
    for (int m = 0; m < 8; ++m) af[m] = *(const bf16x8*)(As_s + aoff[m]);
    bfr[0] = *(const bf16x8*)(Bs_s + boff[0]);
    bfr[1] = *(const bf16x8*)(Bs_s + boff[1]);
    if (s + 3 < NS) stageA(s + 3);
    __builtin_amdgcn_s_barrier();
    __builtin_amdgcn_s_setprio(1);
#pragma unroll
    for (int m = 0; m < 8; ++m) {
      acc[m][0] = __builtin_amdgcn_mfma_f32_16x16x32_bf16(af[m], bfr[0], acc[m][0], 0, 0, 0);
      acc[m][1] = __builtin_amdgcn_mfma_f32_16x16x32_bf16(af[m], bfr[1], acc[m][1], 0, 0, 0);
    }
    __builtin_amdgcn_s_setprio(0);
    __builtin_amdgcn_s_barrier();
    // ---- phase 1: read B n2/n3, stage B(s+3), MFMA n2/n3 ----
    bfr[2] = *(const bf16x8*)(Bs_s + boff[2]);
    bfr[3] = *(const bf16x8*)(Bs_s + boff[3]);
    if (s + 3 < NS) stageB(s + 3);
    __builtin_amdgcn_s_barrier();
    __builtin_amdgcn_s_setprio(1);
#pragma unroll
    for (int m = 0; m < 8; ++m) {
      acc[m][2] = __builtin_amdgcn_mfma_f32_16x16x32_bf16(af[m], bfr[2], acc[m][2], 0, 0, 0);
      acc[m][3] = __builtin_amdgcn_mfma_f32_16x16x32_bf16(af[m], bfr[3], acc[m][3], 0, 0, 0);
    }
    __builtin_amdgcn_s_setprio(0);
    // counted end-of-slice wait: keep 2 slices (8 loads) in flight
    if (s < NS - 3)       asm volatile("s_waitcnt vmcnt(8)" ::: "memory");
    else if (s == NS - 3) asm volatile("s_waitcnt vmcnt(4)" ::: "memory");
    else if (s == NS - 2) asm volatile("s_waitcnt vmcnt(0)" ::: "memory");
    __builtin_amdgcn_s_barrier();
  }

  // epilogue: C/D layout col=lane&15, row=(lane>>4)*4+reg
  const int mb = brow + wr * 128 + k8 * 4;
  const int nb = bcol + wc * 64 + l16;
#pragma unroll
  for (int m = 0; m < 8; ++m) {
#pragma unroll
    for (int n = 0; n < 4; ++n) {
      const int col = nb + n * 16;
#pragma unroll
      for (int r = 0; r < 4; ++r) {
        const int row = mb + m * 16 + r;
        const float v = acc[m][n][r];
        if (col < nbcols) {
          outb[(size_t)row * ldb + col] = __float2bfloat16(v);
        } else {
          outf[(size_t)row * ldf + (col - nbcols)] = v;
        }
      }
    }
  }
}

// ---------------------------------------------------------------------------
// Gated scan, chunked: S=4096 split into 32 chunks of L=128 per sequence.
// qkvg layout: [8192 tokens][4096] bf16, cols [q|k|v|g]; apre fp32 [8192][1024].
// ---------------------------------------------------------------------------
__global__ __launch_bounds__(256) void scan_pass1(
    const __hip_bfloat16* __restrict__ qkvg, const float* __restrict__ apre,
    float* __restrict__ Asum, float* __restrict__ Ysum) {
  const int bc = blockIdx.x;           // b*32 + chunk
  const int d = blockIdx.y * 256 + threadIdx.x;
  const size_t rowbase = (size_t)(bc >> 5) * 4096 + (size_t)(bc & 31) * 128;
  float y = 0.f, Ap = 1.f;
  for (int s = 0; s < 128; ++s) {
    const size_t r = rowbase + s;
    const float kk = __bfloat162float(qkvg[r * 4096 + 1024 + d]);
    const float vv = __bfloat162float(qkvg[r * 4096 + 2048 + d]);
    const float ap = apre[r * 1024 + d];
    const float a = 1.f / (1.f + __expf(-ap));
    y = fmaf(a, y, kk * vv);
    Ap *= a;
  }
  Asum[(size_t)bc * 1024 + d] = Ap;
  Ysum[(size_t)bc * 1024 + d] = y;
}

__global__ __launch_bounds__(256) void scan_pass2(
    const float* __restrict__ Asum, const float* __restrict__ Ysum,
    float* __restrict__ carry) {
  const int idx = blockIdx.x * 256 + threadIdx.x;  // 0..2047
  const int b = idx >> 10, d = idx & 1023;
  float y = 0.f;
  for (int c = 0; c < 32; ++c) {
    const size_t o = (size_t)(b * 32 + c) * 1024 + d;
    carry[o] = y;
    y = fmaf(Asum[o], y, Ysum[o]);
  }
}

__global__ __launch_bounds__(256) void scan_pass3(
    const __hip_bfloat16* __restrict__ qkvg, const float* __restrict__ apre,
    const float* __restrict__ carry, __hip_bfloat16* __restrict__ yact) {
  const int bc = blockIdx.x;
  const int d = blockIdx.y * 256 + threadIdx.x;
  const size_t rowbase = (size_t)(bc >> 5) * 4096 + (size_t)(bc & 31) * 128;
  float y = carry[(size_t)bc * 1024 + d];
  for (int s = 0; s < 128; ++s) {
    const size_t r = rowbase + s;
    const float qq = __bfloat162float(qkvg[r * 4096 + d]);
    const float kk = __bfloat162float(qkvg[r * 4096 + 1024 + d]);
    const float vv = __bfloat162float(qkvg[r * 4096 + 2048 + d]);
    const float gg = __bfloat162float(qkvg[r * 4096 + 3072 + d]);
    const float ap = apre[r * 1024 + d];
    const float a = 1.f / (1.f + __expf(-ap));
    y = fmaf(a, y, kk * vv);
    const float sg = 1.f / (1.f + __expf(-gg));
    yact[r * 1024 + d] = __float2bfloat16(qq * y * gg * sg);
  }
}

// ---------------------------------------------------------------------------
// launch
// ---------------------------------------------------------------------------
extern "C" void kernel_launch(void* const* d_in, const int* in_sizes, int n_in,
                              void* d_out, int out_size, void* d_ws, size_t ws_size,
                              hipStream_t stream) {
  const float* x     = (const float*)d_in[0];
  const float* gamma = (const float*)d_in[1];
  const float* wq    = (const float*)d_in[2];
  const float* wk    = (const float*)d_in[3];
  const float* wv    = (const float*)d_in[4];
  const float* wa    = (const float*)d_in[5];
  const float* wg    = (const float*)d_in[6];
  const float* wo    = (const float*)d_in[7];
  float* out = (float*)d_out;

  char* ws = (char*)d_ws;
  __hip_bfloat16* wcatT = (__hip_bfloat16*)(ws);              // 5120x1024 bf16
  __hip_bfloat16* woT   = (__hip_bfloat16*)(ws + 10485760);   // 1024x1024 bf16
  __hip_bfloat16* xn    = (__hip_bfloat16*)(ws + 12582912);   // 8192x1024 bf16
  __hip_bfloat16* qkvg  = (__hip_bfloat16*)(ws + 29360128);   // 8192x4096 bf16
  float*          apre  = (float*)(ws + 96468992);            // 8192x1024 f32
  __hip_bfloat16* yact  = (__hip_bfloat16*)(ws + 130023424);  // 8192x1024 bf16
  float*          Asum  = (float*)(ws + 146800640);           // 64x1024 f32
  float*          Ysum  = (float*)(ws + 147062784);
  float*          carry = (float*)(ws + 147324928);           // end ~147.6 MB

  wconv_k<<<dim3(32, 32, 6), dim3(32, 8, 1), 0, stream>>>(wq, wk, wv, wa, wg, wo, wcatT, woT);
  rmsnorm_k<<<dim3(8192), dim3(256), 0, stream>>>(x, gamma, xn);
  gemm256<<<dim3(20, 32), dim3(512), 0, stream>>>(
      xn, wcatT, 8192, 5120, 1024, qkvg, 4096, 4096, apre, 1024);
  scan_pass1<<<dim3(64, 4), dim3(256), 0, stream>>>(qkvg, apre, Asum, Ysum);
  scan_pass2<<<dim3(8), dim3(256), 0, stream>>>(Asum, Ysum, carry);
  scan_pass3<<<dim3(64, 4), dim3(256), 0, stream>>>(qkvg, apre, carry, yact);
  gemm256<<<dim3(4, 32), dim3(512), 0, stream>>>(
      yact, woT, 8192, 1024, 1024, (__hip_bfloat16*)nullptr, 0, 0, out, 1024);
}

// Round 3
// 217.716 us; speedup vs baseline: 1.0674x; 1.0131x over previous
//
#include <hip/hip_runtime.h>
#include <hip/hip_bf16.h>
#include <cstdint>
#include <cstddef>

// ---------------------------------------------------------------------------
// GateLoop fused pipeline. bf16 MFMA GEMMs (256-tile, 4-slot K-slice ring,
// ONE barrier per slice, counted vmcnt) + chunked parallel scan.
// B=2, S=4096, D=1024 hard-coded.
// ---------------------------------------------------------------------------

typedef __bf16 bf16x8 __attribute__((ext_vector_type(8)));
typedef float f32x4 __attribute__((ext_vector_type(4)));

__device__ __forceinline__ void gload_lds16(const void* g, void* l) {
  __builtin_amdgcn_global_load_lds(
      (const __attribute__((address_space(1))) void*)g,
      (__attribute__((address_space(3))) void*)l,
      16, 0, 0);
}

// ---------------------------------------------------------------------------
// Weight convert + transpose: dst[n][k] = (bf16) src[k][n]
// ---------------------------------------------------------------------------
__global__ __launch_bounds__(256) void wconv_k(
    const float* __restrict__ wq, const float* __restrict__ wk,
    const float* __restrict__ wv, const float* __restrict__ wa,
    const float* __restrict__ wg, const float* __restrict__ wo,
    __hip_bfloat16* __restrict__ wcatT, __hip_bfloat16* __restrict__ woT) {
  __shared__ float t[32][33];
  const float* src;
  __hip_bfloat16* dst;
  switch (blockIdx.z) {
    case 0: src = wq; dst = wcatT; break;
    case 1: src = wk; dst = wcatT + (size_t)1024 * 1024; break;
    case 2: src = wv; dst = wcatT + (size_t)2048 * 1024; break;
    case 3: src = wg; dst = wcatT + (size_t)3072 * 1024; break;
    case 4: src = wa; dst = wcatT + (size_t)4096 * 1024; break;
    default: src = wo; dst = woT; break;
  }
  const int n0 = blockIdx.x * 32;
  const int k0 = blockIdx.y * 32;
  const int tx = threadIdx.x, ty = threadIdx.y;  // (32, 8)
#pragma unroll
  for (int i = 0; i < 32; i += 8)
    t[ty + i][tx] = src[(size_t)(k0 + ty + i) * 1024 + n0 + tx];
  __syncthreads();
#pragma unroll
  for (int i = 0; i < 32; i += 8)
    dst[(size_t)(n0 + ty + i) * 1024 + k0 + tx] = __float2bfloat16(t[tx][ty + i]);
}

// ---------------------------------------------------------------------------
// RMSNorm (sum-of-squares variant): xn = x * gamma * sqrt(D) * rsqrt(ss+eps)
// ---------------------------------------------------------------------------
__global__ __launch_bounds__(256) void rmsnorm_k(
    const float* __restrict__ x, const float* __restrict__ gamma,
    __hip_bfloat16* __restrict__ xn) {
  const int row = blockIdx.x;
  const int tid = threadIdx.x;
  const float4 xv = ((const float4*)(x + (size_t)row * 1024))[tid];
  float ss = xv.x * xv.x + xv.y * xv.y + xv.z * xv.z + xv.w * xv.w;
#pragma unroll
  for (int off = 32; off >= 1; off >>= 1) ss += __shfl_xor(ss, off, 64);
  __shared__ float wss[4];
  if ((tid & 63) == 0) wss[tid >> 6] = ss;
  __syncthreads();
  const float total = wss[0] + wss[1] + wss[2] + wss[3];
  const float scale = rsqrtf(total + 1e-5f) * 32.0f;  // sqrt(1024) = 32
  const float4 gv = ((const float4*)gamma)[tid];
  union { __hip_bfloat16 h[4]; ushort4 u; } ob;
  ob.h[0] = __float2bfloat16(xv.x * gv.x * scale);
  ob.h[1] = __float2bfloat16(xv.y * gv.y * scale);
  ob.h[2] = __float2bfloat16(xv.z * gv.z * scale);
  ob.h[3] = __float2bfloat16(xv.w * gv.w * scale);
  ((ushort4*)(xn + (size_t)row * 1024))[tid] = ob.u;
}

// ---------------------------------------------------------------------------
// gemm256: C[m][n] = sum_k A[m][k] * Bt[n][k].  256x256 tile, 8 waves (2Mx4N),
// K-slice ring (SK=32, 4 LDS slots), ONE barrier per slice, counted vmcnt(8),
// setprio around MFMA, XOR-swizzled LDS, XCD-bijective block swizzle.
// Requires M%256==0, N%256==0, K%32==0, nwg%8==0.
// Output: n < nbcols -> bf16 outb (ld ldb); else fp32 outf at col n-nbcols.
// ---------------------------------------------------------------------------
__global__ __launch_bounds__(512) void gemm256(
    const __hip_bfloat16* __restrict__ A, const __hip_bfloat16* __restrict__ Bt,
    int M, int N, int K,
    __hip_bfloat16* __restrict__ outb, int ldb, int nbcols,
    float* __restrict__ outf, int ldf) {
  __shared__ __align__(16) unsigned short As[4 * 8192];  // 4 slots x 256x32
  __shared__ __align__(16) unsigned short Bs[4 * 8192];

  const int tid = threadIdx.x;
  const int nwg = gridDim.x * gridDim.y;
  const int bid = blockIdx.y * gridDim.x + blockIdx.x;
  const int swz = (bid & 7) * (nwg >> 3) + (bid >> 3);
  const int brow = (swz / gridDim.x) * 256;
  const int bcol = (swz % gridDim.x) * 256;

  const unsigned short* Ag = (const unsigned short*)A + (size_t)brow * K;
  const unsigned short* Bg = (const unsigned short*)Bt + (size_t)bcol * K;

  const int srow = tid >> 2;                                // 0..127
  const int sch8 = (((tid & 3) ^ ((srow >> 1) & 3)) << 3);  // swizzled k-chunk

  auto stageA = [&](int sl) {
    unsigned short* dst = As + ((sl & 3) << 13);
    const int k0 = sl << 5;
    gload_lds16(Ag + (size_t)srow * K + k0 + sch8, dst + tid * 8);
    gload_lds16(Ag + (size_t)(srow + 128) * K + k0 + sch8, dst + 4096 + tid * 8);
  };
  auto stageB = [&](int sl) {
    unsigned short* dst = Bs + ((sl & 3) << 13);
    const int k0 = sl << 5;
    gload_lds16(Bg + (size_t)srow * K + k0 + sch8, dst + tid * 8);
    gload_lds16(Bg + (size_t)(srow + 128) * K + k0 + sch8, dst + 4096 + tid * 8);
  };

  const int lane = tid & 63;
  const int wid = tid >> 6;
  const int wr = wid >> 2;   // 0..1 : 128-row half
  const int wc = wid & 3;    // 0..3 : 64-col quarter
  const int l16 = lane & 15;
  const int k8 = lane >> 4;

  int aoff[8], boff[4];
#pragma unroll
  for (int m = 0; m < 8; ++m) {
    const int r = wr * 128 + m * 16 + l16;
    aoff[m] = r * 32 + ((k8 ^ ((r >> 1) & 3)) << 3);
  }
#pragma unroll
  for (int n = 0; n < 4; ++n) {
    const int r = wc * 64 + n * 16 + l16;
    boff[n] = r * 32 + ((k8 ^ ((r >> 1) & 3)) << 3);
  }

  f32x4 acc[8][4];
#pragma unroll
  for (int m = 0; m < 8; ++m)
#pragma unroll
    for (int n = 0; n < 4; ++n) acc[m][n] = (f32x4){0.f, 0.f, 0.f, 0.f};

  const int NS = K >> 5;
  stageA(0); stageB(0);
  stageA(1); stageB(1);
  stageA(2); stageB(2);
  asm volatile("s_waitcnt vmcnt(8)" ::: "memory");  // slice 0 landed
  __builtin_amdgcn_s_barrier();

  for (int s = 0; s < NS; ++s) {
    const unsigned short* As_s = As + ((s & 3) << 13);
    const unsigned short* Bs_s = Bs + ((s & 3) << 13);
    bf16x8 af[8], bfr[4];
#pragma unroll
    for (int n = 0; n < 4; ++n) bfr[n] = *(const bf16x8*)(Bs_s + boff[n]);
#pragma unroll
    for (int m = 0; m < 4; ++m) af[m] = *(const bf16x8*)(As_s + aoff[m]);
    if (s + 3 < NS) stageA(s + 3);
#pragma unroll
    for (int m = 4; m < 8; ++m) af[m] = *(const bf16x8*)(As_s + aoff[m]);
    if (s + 3 < NS) stageB(s + 3);
    __builtin_amdgcn_s_setprio(1);
#pragma unroll
    for (int m = 0; m < 8; ++m)
#pragma unroll
      for (int n = 0; n < 4; ++n)
        acc[m][n] = __builtin_amdgcn_mfma_f32_16x16x32_bf16(af[m], bfr[n], acc[m][n], 0, 0, 0);
    __builtin_amdgcn_s_setprio(0);
    // counted end-of-slice wait: keep 2 future slices (8 loads) in flight
    if (s < NS - 3)       asm volatile("s_waitcnt vmcnt(8)" ::: "memory");
    else if (s == NS - 3) asm volatile("s_waitcnt vmcnt(4)" ::: "memory");
    else if (s == NS - 2) asm volatile("s_waitcnt vmcnt(0)" ::: "memory");
    __builtin_amdgcn_s_barrier();
  }

  // epilogue: C/D layout col=lane&15, row=(lane>>4)*4+reg
  const int mb = brow + wr * 128 + k8 * 4;
  const int nb = bcol + wc * 64 + l16;
#pragma unroll
  for (int m = 0; m < 8; ++m) {
#pragma unroll
    for (int n = 0; n < 4; ++n) {
      const int col = nb + n * 16;
#pragma unroll
      for (int r = 0; r < 4; ++r) {
        const int row = mb + m * 16 + r;
        const float v = acc[m][n][r];
        if (col < nbcols) {
          outb[(size_t)row * ldb + col] = __float2bfloat16(v);
        } else {
          outf[(size_t)row * ldf + (col - nbcols)] = v;
        }
      }
    }
  }
}

// ---------------------------------------------------------------------------
// gemm_n128: same schedule, 256x128 tile (for N=1024 -> full-chip grid).
// 8 waves (2Mx4N), per-wave 128x32 output, acc[8][2]. fp32 output only.
// ---------------------------------------------------------------------------
__global__ __launch_bounds__(512) void gemm_n128(
    const __hip_bfloat16* __restrict__ A, const __hip_bfloat16* __restrict__ Bt,
    int M, int N, int K, float* __restrict__ outf, int ldf) {
  __shared__ __align__(16) unsigned short As[4 * 8192];  // 4 slots x 256x32
  __shared__ __align__(16) unsigned short Bs[4 * 4096];  // 4 slots x 128x32

  const int tid = threadIdx.x;
  const int nwg = gridDim.x * gridDim.y;
  const int bid = blockIdx.y * gridDim.x + blockIdx.x;
  const int swz = (bid & 7) * (nwg >> 3) + (bid >> 3);
  const int brow = (swz / gridDim.x) * 256;
  const int bcol = (swz % gridDim.x) * 128;

  const unsigned short* Ag = (const unsigned short*)A + (size_t)brow * K;
  const unsigned short* Bg = (const unsigned short*)Bt + (size_t)bcol * K;

  const int srow = tid >> 2;
  const int sch8 = (((tid & 3) ^ ((srow >> 1) & 3)) << 3);

  auto stageA = [&](int sl) {
    unsigned short* dst = As + ((sl & 3) << 13);
    const int k0 = sl << 5;
    gload_lds16(Ag + (size_t)srow * K + k0 + sch8, dst + tid * 8);
    gload_lds16(Ag + (size_t)(srow + 128) * K + k0 + sch8, dst + 4096 + tid * 8);
  };
  auto stageB = [&](int sl) {  // 128x32 = one 512-thread issue
    unsigned short* dst = Bs + ((sl & 3) << 12);
    const int k0 = sl << 5;
    gload_lds16(Bg + (size_t)srow * K + k0 + sch8, dst + tid * 8);
  };

  const int lane = tid & 63;
  const int wid = tid >> 6;
  const int wr = wid >> 2;   // 0..1 : 128-row half
  const int wc = wid & 3;    // 0..3 : 32-col slice
  const int l16 = lane & 15;
  const int k8 = lane >> 4;

  int aoff[8], boff[2];
#pragma unroll
  for (int m = 0; m < 8; ++m) {
    const int r = wr * 128 + m * 16 + l16;
    aoff[m] = r * 32 + ((k8 ^ ((r >> 1) & 3)) << 3);
  }
#pragma unroll
  for (int n = 0; n < 2; ++n) {
    const int r = wc * 32 + n * 16 + l16;
    boff[n] = r * 32 + ((k8 ^ ((r >> 1) & 3)) << 3);
  }

  f32x4 acc[8][2];
#pragma unroll
  for (int m = 0; m < 8; ++m)
#pragma unroll
    for (int n = 0; n < 2; ++n) acc[m][n] = (f32x4){0.f, 0.f, 0.f, 0.f};

  const int NS = K >> 5;
  stageA(0); stageB(0);
  stageA(1); stageB(1);
  stageA(2); stageB(2);
  asm volatile("s_waitcnt vmcnt(6)" ::: "memory");  // slice 0 (3 ops) landed
  __builtin_amdgcn_s_barrier();

  for (int s = 0; s < NS; ++s) {
    const unsigned short* As_s = As + ((s & 3) << 13);
    const unsigned short* Bs_s = Bs + ((s & 3) << 12);
    bf16x8 af[8], bfr[2];
    bfr[0] = *(const bf16x8*)(Bs_s + boff[0]);
    bfr[1] = *(const bf16x8*)(Bs_s + boff[1]);
#pragma unroll
    for (int m = 0; m < 4; ++m) af[m] = *(const bf16x8*)(As_s + aoff[m]);
    if (s + 3 < NS) stageA(s + 3);
#pragma unroll
    for (int m = 4; m < 8; ++m) af[m] = *(const bf16x8*)(As_s + aoff[m]);
    if (s + 3 < NS) stageB(s + 3);
    __builtin_amdgcn_s_setprio(1);
#pragma unroll
    for (int m = 0; m < 8; ++m)
#pragma unroll
      for (int n = 0; n < 2; ++n)
        acc[m][n] = __builtin_amdgcn_mfma_f32_16x16x32_bf16(af[m], bfr[n], acc[m][n], 0, 0, 0);
    __builtin_amdgcn_s_setprio(0);
    if (s < NS - 3)       asm volatile("s_waitcnt vmcnt(6)" ::: "memory");
    else if (s == NS - 3) asm volatile("s_waitcnt vmcnt(3)" ::: "memory");
    else if (s == NS - 2) asm volatile("s_waitcnt vmcnt(0)" ::: "memory");
    __builtin_amdgcn_s_barrier();
  }

  const int mb = brow + wr * 128 + k8 * 4;
  const int nb = bcol + wc * 32 + l16;
#pragma unroll
  for (int m = 0; m < 8; ++m) {
#pragma unroll
    for (int n = 0; n < 2; ++n) {
      const int col = nb + n * 16;
#pragma unroll
      for (int r = 0; r < 4; ++r) {
        const int row = mb + m * 16 + r;
        outf[(size_t)row * ldf + col] = acc[m][n][r];
      }
    }
  }
}

// ---------------------------------------------------------------------------
// Gated scan, chunked: S=4096 split into 32 chunks of L=128 per sequence.
// qkvg layout: [8192 tokens][4096] bf16, cols [q|k|v|g]; apre fp32 [8192][1024].
// ---------------------------------------------------------------------------
__global__ __launch_bounds__(256) void scan_pass1(
    const __hip_bfloat16* __restrict__ qkvg, const float* __restrict__ apre,
    float* __restrict__ Asum, float* __restrict__ Ysum) {
  const int bc = blockIdx.x;           // b*32 + chunk
  const int d = blockIdx.y * 256 + threadIdx.x;
  const size_t rowbase = (size_t)(bc >> 5) * 4096 + (size_t)(bc & 31) * 128;
  float y = 0.f, Ap = 1.f;
  for (int s = 0; s < 128; ++s) {
    const size_t r = rowbase + s;
    const float kk = __bfloat162float(qkvg[r * 4096 + 1024 + d]);
    const float vv = __bfloat162float(qkvg[r * 4096 + 2048 + d]);
    const float ap = apre[r * 1024 + d];
    const float a = 1.f / (1.f + __expf(-ap));
    y = fmaf(a, y, kk * vv);
    Ap *= a;
  }
  Asum[(size_t)bc * 1024 + d] = Ap;
  Ysum[(size_t)bc * 1024 + d] = y;
}

__global__ __launch_bounds__(256) void scan_pass2(
    const float* __restrict__ Asum, const float* __restrict__ Ysum,
    float* __restrict__ carry) {
  const int idx = blockIdx.x * 256 + threadIdx.x;  // 0..2047
  const int b = idx >> 10, d = idx & 1023;
  float y = 0.f;
  for (int c = 0; c < 32; ++c) {
    const size_t o = (size_t)(b * 32 + c) * 1024 + d;
    carry[o] = y;
    y = fmaf(Asum[o], y, Ysum[o]);
  }
}

__global__ __launch_bounds__(256) void scan_pass3(
    const __hip_bfloat16* __restrict__ qkvg, const float* __restrict__ apre,
    const float* __restrict__ carry, __hip_bfloat16* __restrict__ yact) {
  const int bc = blockIdx.x;
  const int d = blockIdx.y * 256 + threadIdx.x;
  const size_t rowbase = (size_t)(bc >> 5) * 4096 + (size_t)(bc & 31) * 128;
  float y = carry[(size_t)bc * 1024 + d];
  for (int s = 0; s < 128; ++s) {
    const size_t r = rowbase + s;
    const float qq = __bfloat162float(qkvg[r * 4096 + d]);
    const float kk = __bfloat162float(qkvg[r * 4096 + 1024 + d]);
    const float vv = __bfloat162float(qkvg[r * 4096 + 2048 + d]);
    const float gg = __bfloat162float(qkvg[r * 4096 + 3072 + d]);
    const float ap = apre[r * 1024 + d];
    const float a = 1.f / (1.f + __expf(-ap));
    y = fmaf(a, y, kk * vv);
    const float sg = 1.f / (1.f + __expf(-gg));
    yact[r * 1024 + d] = __float2bfloat16(qq * y * gg * sg);
  }
}

// ---------------------------------------------------------------------------
// launch
// ---------------------------------------------------------------------------
extern "C" void kernel_launch(void* const* d_in, const int* in_sizes, int n_in,
                              void* d_out, int out_size, void* d_ws, size_t ws_size,
                              hipStream_t stream) {
  const float* x     = (const float*)d_in[0];
  const float* gamma = (const float*)d_in[1];
  const float* wq    = (const float*)d_in[2];
  const float* wk    = (const float*)d_in[3];
  const float* wv    = (const float*)d_in[4];
  const float* wa    = (const float*)d_in[5];
  const float* wg    = (const float*)d_in[6];
  const float* wo    = (const float*)d_in[7];
  float* out = (float*)d_out;

  char* ws = (char*)d_ws;
  __hip_bfloat16* wcatT = (__hip_bfloat16*)(ws);              // 5120x1024 bf16
  __hip_bfloat16* woT   = (__hip_bfloat16*)(ws + 10485760);   // 1024x1024 bf16
  __hip_bfloat16* xn    = (__hip_bfloat16*)(ws + 12582912);   // 8192x1024 bf16
  __hip_bfloat16* qkvg  = (__hip_bfloat16*)(ws + 29360128);   // 8192x4096 bf16
  float*          apre  = (float*)(ws + 96468992);            // 8192x1024 f32
  __hip_bfloat16* yact  = (__hip_bfloat16*)(ws + 130023424);  // 8192x1024 bf16
  float*          Asum  = (float*)(ws + 146800640);           // 64x1024 f32
  float*          Ysum  = (float*)(ws + 147062784);
  float*          carry = (float*)(ws + 147324928);           // end ~147.6 MB

  wconv_k<<<dim3(32, 32, 6), dim3(32, 8, 1), 0, stream>>>(wq, wk, wv, wa, wg, wo, wcatT, woT);
  rmsnorm_k<<<dim3(8192), dim3(256), 0, stream>>>(x, gamma, xn);
  gemm256<<<dim3(20, 32), dim3(512), 0, stream>>>(
      xn, wcatT, 8192, 5120, 1024, qkvg, 4096, 4096, apre, 1024);
  scan_pass1<<<dim3(64, 4), dim3(256), 0, stream>>>(qkvg, apre, Asum, Ysum);
  scan_pass2<<<dim3(8), dim3(256), 0, stream>>>(Asum, Ysum, carry);
  scan_pass3<<<dim3(64, 4), dim3(256), 0, stream>>>(qkvg, apre, carry, yact);
  gemm_n128<<<dim3(8, 32), dim3(512), 0, stream>>>(
      yact, woT, 8192, 1024, 1024, out, 1024);
}

// Round 4
// 209.728 us; speedup vs baseline: 1.1081x; 1.0381x over previous
//
#include <hip/hip_runtime.h>
#include <hip/hip_bf16.h>
#include <cstdint>
#include <cstddef>

// ---------------------------------------------------------------------------
// GateLoop fused pipeline. bf16 MFMA GEMMs (256-tile, 4-slot K-slice ring,
// register-pipelined fragments, counted vmcnt) + chunked parallel scan.
// B=2, S=4096, D=1024 hard-coded.
// ---------------------------------------------------------------------------

typedef __bf16 bf16x8 __attribute__((ext_vector_type(8)));
typedef float f32x4 __attribute__((ext_vector_type(4)));

__device__ __forceinline__ void gload_lds16(const void* g, void* l) {
  __builtin_amdgcn_global_load_lds(
      (const __attribute__((address_space(1))) void*)g,
      (__attribute__((address_space(3))) void*)l,
      16, 0, 0);
}

// ---------------------------------------------------------------------------
// Weight convert + transpose: dst[n][k] = (bf16) src[k][n]
// ---------------------------------------------------------------------------
__global__ __launch_bounds__(256) void wconv_k(
    const float* __restrict__ wq, const float* __restrict__ wk,
    const float* __restrict__ wv, const float* __restrict__ wa,
    const float* __restrict__ wg, const float* __restrict__ wo,
    __hip_bfloat16* __restrict__ wcatT, __hip_bfloat16* __restrict__ woT) {
  __shared__ float t[32][33];
  const float* src;
  __hip_bfloat16* dst;
  switch (blockIdx.z) {
    case 0: src = wq; dst = wcatT; break;
    case 1: src = wk; dst = wcatT + (size_t)1024 * 1024; break;
    case 2: src = wv; dst = wcatT + (size_t)2048 * 1024; break;
    case 3: src = wg; dst = wcatT + (size_t)3072 * 1024; break;
    case 4: src = wa; dst = wcatT + (size_t)4096 * 1024; break;
    default: src = wo; dst = woT; break;
  }
  const int n0 = blockIdx.x * 32;
  const int k0 = blockIdx.y * 32;
  const int tx = threadIdx.x, ty = threadIdx.y;  // (32, 8)
#pragma unroll
  for (int i = 0; i < 32; i += 8)
    t[ty + i][tx] = src[(size_t)(k0 + ty + i) * 1024 + n0 + tx];
  __syncthreads();
#pragma unroll
  for (int i = 0; i < 32; i += 8)
    dst[(size_t)(n0 + ty + i) * 1024 + k0 + tx] = __float2bfloat16(t[tx][ty + i]);
}

// ---------------------------------------------------------------------------
// RMSNorm (sum-of-squares variant): xn = x * gamma * sqrt(D) * rsqrt(ss+eps)
// ---------------------------------------------------------------------------
__global__ __launch_bounds__(256) void rmsnorm_k(
    const float* __restrict__ x, const float* __restrict__ gamma,
    __hip_bfloat16* __restrict__ xn) {
  const int row = blockIdx.x;
  const int tid = threadIdx.x;
  const float4 xv = ((const float4*)(x + (size_t)row * 1024))[tid];
  float ss = xv.x * xv.x + xv.y * xv.y + xv.z * xv.z + xv.w * xv.w;
#pragma unroll
  for (int off = 32; off >= 1; off >>= 1) ss += __shfl_xor(ss, off, 64);
  __shared__ float wss[4];
  if ((tid & 63) == 0) wss[tid >> 6] = ss;
  __syncthreads();
  const float total = wss[0] + wss[1] + wss[2] + wss[3];
  const float scale = rsqrtf(total + 1e-5f) * 32.0f;  // sqrt(1024) = 32
  const float4 gv = ((const float4*)gamma)[tid];
  union { __hip_bfloat16 h[4]; ushort4 u; } ob;
  ob.h[0] = __float2bfloat16(xv.x * gv.x * scale);
  ob.h[1] = __float2bfloat16(xv.y * gv.y * scale);
  ob.h[2] = __float2bfloat16(xv.z * gv.z * scale);
  ob.h[3] = __float2bfloat16(xv.w * gv.w * scale);
  ((ushort4*)(xn + (size_t)row * 1024))[tid] = ob.u;
}

// ---------------------------------------------------------------------------
// gemm256: C[m][n] = sum_k A[m][k] * Bt[n][k].  256x256 tile, 8 waves (2Mx4N),
// K-slice ring (SK=32, 4 LDS slots). Register pipeline: B-frags prefetched one
// slice ahead (bfE/bfO ping-pong); A-frag reads interleaved with MFMA groups.
// Counted vmcnt(4) (1 stage-set in flight), one barrier/slice.
// Requires M%256==0, N%256==0, K%32==0, K>=128, nwg%8==0.
// Output: n < nbcols -> bf16 outb (ld ldb); else fp32 outf at col n-nbcols.
// ---------------------------------------------------------------------------
__global__ __launch_bounds__(512) void gemm256(
    const __hip_bfloat16* __restrict__ A, const __hip_bfloat16* __restrict__ Bt,
    int M, int N, int K,
    __hip_bfloat16* __restrict__ outb, int ldb, int nbcols,
    float* __restrict__ outf, int ldf) {
  __shared__ __align__(16) unsigned short As[4 * 8192];  // 4 slots x 256x32
  __shared__ __align__(16) unsigned short Bs[4 * 8192];

  const int tid = threadIdx.x;
  const int nwg = gridDim.x * gridDim.y;
  const int bid = blockIdx.y * gridDim.x + blockIdx.x;
  const int swz = (bid & 7) * (nwg >> 3) + (bid >> 3);
  const int brow = (swz / gridDim.x) * 256;
  const int bcol = (swz % gridDim.x) * 256;

  const unsigned short* Ag = (const unsigned short*)A + (size_t)brow * K;
  const unsigned short* Bg = (const unsigned short*)Bt + (size_t)bcol * K;

  const int srow = tid >> 2;                                // 0..127
  const int sch8 = (((tid & 3) ^ ((srow >> 1) & 3)) << 3);  // swizzled k-chunk

  auto stageAB = [&](int sl) {
    unsigned short* dA = As + ((sl & 3) << 13);
    unsigned short* dB = Bs + ((sl & 3) << 13);
    const int k0 = sl << 5;
    gload_lds16(Ag + (size_t)srow * K + k0 + sch8, dA + tid * 8);
    gload_lds16(Ag + (size_t)(srow + 128) * K + k0 + sch8, dA + 4096 + tid * 8);
    gload_lds16(Bg + (size_t)srow * K + k0 + sch8, dB + tid * 8);
    gload_lds16(Bg + (size_t)(srow + 128) * K + k0 + sch8, dB + 4096 + tid * 8);
  };

  const int lane = tid & 63;
  const int wid = tid >> 6;
  const int wr = wid >> 2;   // 0..1 : 128-row half
  const int wc = wid & 3;    // 0..3 : 64-col quarter
  const int l16 = lane & 15;
  const int k8 = lane >> 4;

  int aoff[8], boff[4];
#pragma unroll
  for (int m = 0; m < 8; ++m) {
    const int r = wr * 128 + m * 16 + l16;
    aoff[m] = r * 32 + ((k8 ^ ((r >> 1) & 3)) << 3);
  }
#pragma unroll
  for (int n = 0; n < 4; ++n) {
    const int r = wc * 64 + n * 16 + l16;
    boff[n] = r * 32 + ((k8 ^ ((r >> 1) & 3)) << 3);
  }

  f32x4 acc[8][4];
#pragma unroll
  for (int m = 0; m < 8; ++m)
#pragma unroll
    for (int n = 0; n < 4; ++n) acc[m][n] = (f32x4){0.f, 0.f, 0.f, 0.f};

  const int NS = K >> 5;  // >= 4, even
  stageAB(0); stageAB(1); stageAB(2);
  asm volatile("s_waitcnt vmcnt(4)" ::: "memory");  // sets 0,1 landed
  __builtin_amdgcn_s_barrier();

  bf16x8 bfE[4], bfO[4];
  {
    const unsigned short* B0 = Bs;  // slot 0
#pragma unroll
    for (int n = 0; n < 4; ++n) bfE[n] = *(const bf16x8*)(B0 + boff[n]);
  }

  // end-of-slice wait+barrier policy
  auto slice_end = [&](int t) {
    if (t <= NS - 4) {
      asm volatile("s_waitcnt vmcnt(4)" ::: "memory");
      __builtin_amdgcn_s_barrier();
    } else if (t == NS - 3) {
      asm volatile("s_waitcnt vmcnt(0)" ::: "memory");
      __builtin_amdgcn_s_barrier();
    }  // t >= NS-2: no stages outstanding, no overwrite hazard
  };

  for (int s = 0; s < NS; s += 2) {
    // -------- even slice s: consume bfE, prefetch bfO (slice s+1) --------
    {
      const unsigned short* As_s = As + ((s & 3) << 13);
      const unsigned short* Bnx = Bs + (((s + 1) & 3) << 13);
      bf16x8 af[8];
      af[0] = *(const bf16x8*)(As_s + aoff[0]);
      af[1] = *(const bf16x8*)(As_s + aoff[1]);
#pragma unroll
      for (int n = 0; n < 4; ++n) bfO[n] = *(const bf16x8*)(Bnx + boff[n]);
      if (s + 3 < NS) stageAB(s + 3);
      __builtin_amdgcn_s_setprio(1);
#pragma unroll
      for (int m = 0; m < 8; ++m) {
        if (m < 6) af[m + 2] = *(const bf16x8*)(As_s + aoff[m + 2]);
#pragma unroll
        for (int n = 0; n < 4; ++n)
          acc[m][n] = __builtin_amdgcn_mfma_f32_16x16x32_bf16(af[m], bfE[n], acc[m][n], 0, 0, 0);
      }
      __builtin_amdgcn_s_setprio(0);
      slice_end(s);
    }
    // -------- odd slice s+1: consume bfO, prefetch bfE (slice s+2) --------
    {
      const unsigned short* As_s = As + (((s + 1) & 3) << 13);
      bf16x8 af[8];
      af[0] = *(const bf16x8*)(As_s + aoff[0]);
      af[1] = *(const bf16x8*)(As_s + aoff[1]);
      if (s + 2 < NS) {
        const unsigned short* Bnx = Bs + (((s + 2) & 3) << 13);
#pragma unroll
        for (int n = 0; n < 4; ++n) bfE[n] = *(const bf16x8*)(Bnx + boff[n]);
      }
      if (s + 4 < NS) stageAB(s + 4);
      __builtin_amdgcn_s_setprio(1);
#pragma unroll
      for (int m = 0; m < 8; ++m) {
        if (m < 6) af[m + 2] = *(const bf16x8*)(As_s + aoff[m + 2]);
#pragma unroll
        for (int n = 0; n < 4; ++n)
          acc[m][n] = __builtin_amdgcn_mfma_f32_16x16x32_bf16(af[m], bfO[n], acc[m][n], 0, 0, 0);
      }
      __builtin_amdgcn_s_setprio(0);
      slice_end(s + 1);
    }
  }

  // epilogue: C/D layout col=lane&15, row=(lane>>4)*4+reg
  const int mb = brow + wr * 128 + k8 * 4;
  const int nb = bcol + wc * 64 + l16;
#pragma unroll
  for (int m = 0; m < 8; ++m) {
#pragma unroll
    for (int n = 0; n < 4; ++n) {
      const int col = nb + n * 16;
#pragma unroll
      for (int r = 0; r < 4; ++r) {
        const int row = mb + m * 16 + r;
        const float v = acc[m][n][r];
        if (col < nbcols) {
          outb[(size_t)row * ldb + col] = __float2bfloat16(v);
        } else {
          outf[(size_t)row * ldf + (col - nbcols)] = v;
        }
      }
    }
  }
}

// ---------------------------------------------------------------------------
// gemm_n128: same schedule, 256x128 tile (N=1024 -> 256 blocks, full chip).
// 8 waves (2Mx4N), per-wave 128x32 output, acc[8][2]. fp32 output only.
// ---------------------------------------------------------------------------
__global__ __launch_bounds__(512) void gemm_n128(
    const __hip_bfloat16* __restrict__ A, const __hip_bfloat16* __restrict__ Bt,
    int M, int N, int K, float* __restrict__ outf, int ldf) {
  __shared__ __align__(16) unsigned short As[4 * 8192];  // 4 slots x 256x32
  __shared__ __align__(16) unsigned short Bs[4 * 4096];  // 4 slots x 128x32

  const int tid = threadIdx.x;
  const int nwg = gridDim.x * gridDim.y;
  const int bid = blockIdx.y * gridDim.x + blockIdx.x;
  const int swz = (bid & 7) * (nwg >> 3) + (bid >> 3);
  const int brow = (swz / gridDim.x) * 256;
  const int bcol = (swz % gridDim.x) * 128;

  const unsigned short* Ag = (const unsigned short*)A + (size_t)brow * K;
  const unsigned short* Bg = (const unsigned short*)Bt + (size_t)bcol * K;

  const int srow = tid >> 2;
  const int sch8 = (((tid & 3) ^ ((srow >> 1) & 3)) << 3);

  auto stageAB = [&](int sl) {
    unsigned short* dA = As + ((sl & 3) << 13);
    unsigned short* dB = Bs + ((sl & 3) << 12);
    const int k0 = sl << 5;
    gload_lds16(Ag + (size_t)srow * K + k0 + sch8, dA + tid * 8);
    gload_lds16(Ag + (size_t)(srow + 128) * K + k0 + sch8, dA + 4096 + tid * 8);
    gload_lds16(Bg + (size_t)srow * K + k0 + sch8, dB + tid * 8);
  };

  const int lane = tid & 63;
  const int wid = tid >> 6;
  const int wr = wid >> 2;   // 0..1 : 128-row half
  const int wc = wid & 3;    // 0..3 : 32-col slice
  const int l16 = lane & 15;
  const int k8 = lane >> 4;

  int aoff[8], boff[2];
#pragma unroll
  for (int m = 0; m < 8; ++m) {
    const int r = wr * 128 + m * 16 + l16;
    aoff[m] = r * 32 + ((k8 ^ ((r >> 1) & 3)) << 3);
  }
#pragma unroll
  for (int n = 0; n < 2; ++n) {
    const int r = wc * 32 + n * 16 + l16;
    boff[n] = r * 32 + ((k8 ^ ((r >> 1) & 3)) << 3);
  }

  f32x4 acc[8][2];
#pragma unroll
  for (int m = 0; m < 8; ++m)
#pragma unroll
    for (int n = 0; n < 2; ++n) acc[m][n] = (f32x4){0.f, 0.f, 0.f, 0.f};

  const int NS = K >> 5;
  stageAB(0); stageAB(1); stageAB(2);
  asm volatile("s_waitcnt vmcnt(3)" ::: "memory");  // sets 0,1 landed
  __builtin_amdgcn_s_barrier();

  bf16x8 bfE[2], bfO[2];
  {
    const unsigned short* B0 = Bs;
    bfE[0] = *(const bf16x8*)(B0 + boff[0]);
    bfE[1] = *(const bf16x8*)(B0 + boff[1]);
  }

  auto slice_end = [&](int t) {
    if (t <= NS - 4) {
      asm volatile("s_waitcnt vmcnt(3)" ::: "memory");
      __builtin_amdgcn_s_barrier();
    } else if (t == NS - 3) {
      asm volatile("s_waitcnt vmcnt(0)" ::: "memory");
      __builtin_amdgcn_s_barrier();
    }
  };

  for (int s = 0; s < NS; s += 2) {
    {
      const unsigned short* As_s = As + ((s & 3) << 13);
      const unsigned short* Bnx = Bs + (((s + 1) & 3) << 12);
      bf16x8 af[8];
      af[0] = *(const bf16x8*)(As_s + aoff[0]);
      af[1] = *(const bf16x8*)(As_s + aoff[1]);
      bfO[0] = *(const bf16x8*)(Bnx + boff[0]);
      bfO[1] = *(const bf16x8*)(Bnx + boff[1]);
      if (s + 3 < NS) stageAB(s + 3);
      __builtin_amdgcn_s_setprio(1);
#pragma unroll
      for (int m = 0; m < 8; ++m) {
        if (m < 6) af[m + 2] = *(const bf16x8*)(As_s + aoff[m + 2]);
        acc[m][0] = __builtin_amdgcn_mfma_f32_16x16x32_bf16(af[m], bfE[0], acc[m][0], 0, 0, 0);
        acc[m][1] = __builtin_amdgcn_mfma_f32_16x16x32_bf16(af[m], bfE[1], acc[m][1], 0, 0, 0);
      }
      __builtin_amdgcn_s_setprio(0);
      slice_end(s);
    }
    {
      const unsigned short* As_s = As + (((s + 1) & 3) << 13);
      bf16x8 af[8];
      af[0] = *(const bf16x8*)(As_s + aoff[0]);
      af[1] = *(const bf16x8*)(As_s + aoff[1]);
      if (s + 2 < NS) {
        const unsigned short* Bnx = Bs + (((s + 2) & 3) << 12);
        bfE[0] = *(const bf16x8*)(Bnx + boff[0]);
        bfE[1] = *(const bf16x8*)(Bnx + boff[1]);
      }
      if (s + 4 < NS) stageAB(s + 4);
      __builtin_amdgcn_s_setprio(1);
#pragma unroll
      for (int m = 0; m < 8; ++m) {
        if (m < 6) af[m + 2] = *(const bf16x8*)(As_s + aoff[m + 2]);
        acc[m][0] = __builtin_amdgcn_mfma_f32_16x16x32_bf16(af[m], bfO[0], acc[m][0], 0, 0, 0);
        acc[m][1] = __builtin_amdgcn_mfma_f32_16x16x32_bf16(af[m], bfO[1], acc[m][1], 0, 0, 0);
      }
      __builtin_amdgcn_s_setprio(0);
      slice_end(s + 1);
    }
  }

  const int mb = brow + wr * 128 + k8 * 4;
  const int nb = bcol + wc * 32 + l16;
#pragma unroll
  for (int m = 0; m < 8; ++m) {
#pragma unroll
    for (int n = 0; n < 2; ++n) {
      const int col = nb + n * 16;
#pragma unroll
      for (int r = 0; r < 4; ++r) {
        const int row = mb + m * 16 + r;
        outf[(size_t)row * ldf + col] = acc[m][n][r];
      }
    }
  }
}

// ---------------------------------------------------------------------------
// Gated scan, chunked: S=4096 split into 32 chunks of L=128 per sequence.
// qkvg layout: [8192 tokens][4096] bf16, cols [q|k|v|g]; apre fp32 [8192][1024].
// ---------------------------------------------------------------------------
__global__ __launch_bounds__(256) void scan_pass1(
    const __hip_bfloat16* __restrict__ qkvg, const float* __restrict__ apre,
    float* __restrict__ Asum, float* __restrict__ Ysum) {
  const int bc = blockIdx.x;           // b*32 + chunk
  const int d = blockIdx.y * 256 + threadIdx.x;
  const size_t rowbase = (size_t)(bc >> 5) * 4096 + (size_t)(bc & 31) * 128;
  float y = 0.f, Ap = 1.f;
  for (int s = 0; s < 128; ++s) {
    const size_t r = rowbase + s;
    const float kk = __bfloat162float(qkvg[r * 4096 + 1024 + d]);
    const float vv = __bfloat162float(qkvg[r * 4096 + 2048 + d]);
    const float ap = apre[r * 1024 + d];
    const float a = 1.f / (1.f + __expf(-ap));
    y = fmaf(a, y, kk * vv);
    Ap *= a;
  }
  Asum[(size_t)bc * 1024 + d] = Ap;
  Ysum[(size_t)bc * 1024 + d] = y;
}

__global__ __launch_bounds__(256) void scan_pass2(
    const float* __restrict__ Asum, const float* __restrict__ Ysum,
    float* __restrict__ carry) {
  const int idx = blockIdx.x * 256 + threadIdx.x;  // 0..2047
  const int b = idx >> 10, d = idx & 1023;
  float y = 0.f;
  for (int c = 0; c < 32; ++c) {
    const size_t o = (size_t)(b * 32 + c) * 1024 + d;
    carry[o] = y;
    y = fmaf(Asum[o], y, Ysum[o]);
  }
}

__global__ __launch_bounds__(256) void scan_pass3(
    const __hip_bfloat16* __restrict__ qkvg, const float* __restrict__ apre,
    const float* __restrict__ carry, __hip_bfloat16* __restrict__ yact) {
  const int bc = blockIdx.x;
  const int d = blockIdx.y * 256 + threadIdx.x;
  const size_t rowbase = (size_t)(bc >> 5) * 4096 + (size_t)(bc & 31) * 128;
  float y = carry[(size_t)bc * 1024 + d];
  for (int s = 0; s < 128; ++s) {
    const size_t r = rowbase + s;
    const float qq = __bfloat162float(qkvg[r * 4096 + d]);
    const float kk = __bfloat162float(qkvg[r * 4096 + 1024 + d]);
    const float vv = __bfloat162float(qkvg[r * 4096 + 2048 + d]);
    const float gg = __bfloat162float(qkvg[r * 4096 + 3072 + d]);
    const float ap = apre[r * 1024 + d];
    const float a = 1.f / (1.f + __expf(-ap));
    y = fmaf(a, y, kk * vv);
    const float sg = 1.f / (1.f + __expf(-gg));
    yact[r * 1024 + d] = __float2bfloat16(qq * y * gg * sg);
  }
}

// ---------------------------------------------------------------------------
// launch
// ---------------------------------------------------------------------------
extern "C" void kernel_launch(void* const* d_in, const int* in_sizes, int n_in,
                              void* d_out, int out_size, void* d_ws, size_t ws_size,
                              hipStream_t stream) {
  const float* x     = (const float*)d_in[0];
  const float* gamma = (const float*)d_in[1];
  const float* wq    = (const float*)d_in[2];
  const float* wk    = (const float*)d_in[3];
  const float* wv    = (const float*)d_in[4];
  const float* wa    = (const float*)d_in[5];
  const float* wg    = (const float*)d_in[6];
  const float* wo    = (const float*)d_in[7];
  float* out = (float*)d_out;

  char* ws = (char*)d_ws;
  __hip_bfloat16* wcatT = (__hip_bfloat16*)(ws);              // 5120x1024 bf16
  __hip_bfloat16* woT   = (__hip_bfloat16*)(ws + 10485760);   // 1024x1024 bf16
  __hip_bfloat16* xn    = (__hip_bfloat16*)(ws + 12582912);   // 8192x1024 bf16
  __hip_bfloat16* qkvg  = (__hip_bfloat16*)(ws + 29360128);   // 8192x4096 bf16
  float*          apre  = (float*)(ws + 96468992);            // 8192x1024 f32
  __hip_bfloat16* yact  = (__hip_bfloat16*)(ws + 130023424);  // 8192x1024 bf16
  float*          Asum  = (float*)(ws + 146800640);           // 64x1024 f32
  float*          Ysum  = (float*)(ws + 147062784);
  float*          carry = (float*)(ws + 147324928);           // end ~147.6 MB

  wconv_k<<<dim3(32, 32, 6), dim3(32, 8, 1), 0, stream>>>(wq, wk, wv, wa, wg, wo, wcatT, woT);
  rmsnorm_k<<<dim3(8192), dim3(256), 0, stream>>>(x, gamma, xn);
  gemm256<<<dim3(20, 32), dim3(512), 0, stream>>>(
      xn, wcatT, 8192, 5120, 1024, qkvg, 4096, 4096, apre, 1024);
  scan_pass1<<<dim3(64, 4), dim3(256), 0, stream>>>(qkvg, apre, Asum, Ysum);
  scan_pass2<<<dim3(8), dim3(256), 0, stream>>>(Asum, Ysum, carry);
  scan_pass3<<<dim3(64, 4), dim3(256), 0, stream>>>(qkvg, apre, carry, yact);
  gemm_n128<<<dim3(8, 32), dim3(512), 0, stream>>>(
      yact, woT, 8192, 1024, 1024, out, 1024);
}